// Round 2
// baseline (502.278 us; speedup 1.0000x reference)
//
#include <hip/hip_runtime.h>
#include <hip/hip_bf16.h>
#include <math.h>

#define BB 64
#define TT 500
#define DD 64
#define SS 50

__device__ __forceinline__ float sigmoidf_(float x) { return 1.0f / (1.0f + __expf(-x)); }

// ---------------------------------------------------------------------------
// Kernel 1: per (b,t) — embeddings gather, w = softmax(k·Mk^T), e, a
// one wave (64 threads) per (b,t); thread = d
// ---------------------------------------------------------------------------
__global__ __launch_bounds__(64) void k1_precompute(
    const int* __restrict__ concept_seq,
    const int* __restrict__ correct_seq,
    const int* __restrict__ num_concept,
    const float* __restrict__ embed_key,
    const float* __restrict__ embed_value,
    const float* __restrict__ Mk,
    const float* __restrict__ We, const float* __restrict__ be,
    const float* __restrict__ Wa, const float* __restrict__ ba,
    float* __restrict__ wOut, float* __restrict__ eOut, float* __restrict__ aOut)
{
    const int bt = blockIdx.x;
    const int lane = threadIdx.x;
    const int c = concept_seq[bt];
    const int x = c + num_concept[0] * correct_seq[bt];

    __shared__ float kS[DD];
    __shared__ float vS[DD];
    kS[lane] = embed_key[c * DD + lane];
    vS[lane] = embed_value[x * DD + lane];
    __syncthreads();

    // scores for s = lane (lanes 0..49)
    float sc = -1e30f;
    if (lane < SS) {
        float acc = 0.f;
        #pragma unroll
        for (int dd = 0; dd < DD; ++dd)
            acc = fmaf(kS[dd], Mk[lane * DD + dd], acc);
        sc = acc;
    }
    // wave softmax over 64 lanes (lanes >= 50 contribute -inf / 0)
    float m = sc;
    #pragma unroll
    for (int off = 32; off >= 1; off >>= 1)
        m = fmaxf(m, __shfl_xor(m, off));
    float ex = (lane < SS) ? __expf(sc - m) : 0.f;
    float ssum = ex;
    #pragma unroll
    for (int off = 32; off >= 1; off >>= 1)
        ssum += __shfl_xor(ssum, off);
    if (lane < SS)
        wOut[(size_t)bt * SS + lane] = ex / ssum;

    // e = sigmoid(v@We + be), a = tanh(v@Wa + ba); thread d = output column
    float acc_e = be[lane];
    float acc_a = ba[lane];
    #pragma unroll
    for (int i = 0; i < DD; ++i) {
        const float vi = vS[i];
        acc_e = fmaf(vi, We[i * DD + lane], acc_e);
        acc_a = fmaf(vi, Wa[i * DD + lane], acc_a);
    }
    eOut[(size_t)bt * DD + lane] = sigmoidf_(acc_e);
    aOut[(size_t)bt * DD + lane] = tanhf(acc_a);
}

// ---------------------------------------------------------------------------
// Kernel 2: the sequential scan. One block per b; thread d owns Mv[:,d] in
// 50 VGPRs. Per step: r[d] = sum_s w[s]*Mv[s]; Mv[s] -= w[s]*(e*Mv[s]-a).
// w loads are block-uniform -> scalar loads.
// ---------------------------------------------------------------------------
__global__ __launch_bounds__(64) void k2_scan(
    const float* __restrict__ wIn,
    const float* __restrict__ eIn,
    const float* __restrict__ aIn,
    const float* __restrict__ Mv0,
    float* __restrict__ rOut)
{
    const int b = blockIdx.x;
    const int d = threadIdx.x;

    float Mv[SS];
    #pragma unroll
    for (int s = 0; s < SS; ++s)
        Mv[s] = Mv0[s * DD + d];

    const float* wp = wIn + (size_t)b * TT * SS;
    const float* ep = eIn + (size_t)b * TT * DD + d;
    const float* ap = aIn + (size_t)b * TT * DD + d;
    float* rp = rOut + (size_t)b * TT * DD + d;

    for (int t = 0; t < TT; ++t) {
        const float e = ep[0];
        const float a = ap[0];
        float racc0 = 0.f, racc1 = 0.f, racc2 = 0.f, racc3 = 0.f;
        #pragma unroll
        for (int s = 0; s < SS; ++s) {
            const float ws = wp[s];
            const float mv = Mv[s];
            // r uses Mv BEFORE the update
            if ((s & 3) == 0)      racc0 = fmaf(ws, mv, racc0);
            else if ((s & 3) == 1) racc1 = fmaf(ws, mv, racc1);
            else if ((s & 3) == 2) racc2 = fmaf(ws, mv, racc2);
            else                   racc3 = fmaf(ws, mv, racc3);
            const float t2 = fmaf(e, mv, -a);   // e*Mv - a
            Mv[s] = fmaf(-ws, t2, mv);          // Mv - w*(e*Mv - a)
        }
        rp[0] = (racc0 + racc1) + (racc2 + racc3);
        wp += SS; ep += DD; ap += DD; rp += DD;
    }
}

// ---------------------------------------------------------------------------
// Kernel 3: output head. One wave per (b,t); thread = output column j of f.
// ---------------------------------------------------------------------------
__global__ __launch_bounds__(64) void k3_output(
    const int* __restrict__ concept_seq,
    const float* __restrict__ embed_key,
    const float* __restrict__ rIn,
    const float* __restrict__ Wf, const float* __restrict__ bf,
    const float* __restrict__ Wab, const float* __restrict__ bab,
    const float* __restrict__ Wd, const float* __restrict__ bd,
    float* __restrict__ out)
{
    const int bt = blockIdx.x;
    const int lane = threadIdx.x;
    __shared__ float rS[DD];
    __shared__ float kS[DD];
    const int c = concept_seq[bt];
    kS[lane] = embed_key[c * DD + lane];
    rS[lane] = rIn[(size_t)bt * DD + lane];
    __syncthreads();

    float acc = bf[lane];
    #pragma unroll
    for (int i = 0; i < DD; ++i)
        acc = fmaf(rS[i], Wf[i * DD + lane], acc);
    #pragma unroll
    for (int i = 0; i < DD; ++i)
        acc = fmaf(kS[i], Wf[(DD + i) * DD + lane], acc);
    const float f = tanhf(acc);

    float p = f * Wab[lane];
    float q = kS[lane] * Wd[lane];
    #pragma unroll
    for (int off = 32; off >= 1; off >>= 1) {
        p += __shfl_xor(p, off);
        q += __shfl_xor(q, off);
    }
    if (lane == 0) {
        const float stu  = tanhf(p + bab[0]);
        const float diff = tanhf(q + bd[0]);
        out[bt] = sigmoidf_(3.0f * stu - diff);
    }
}

// ---------------------------------------------------------------------------
extern "C" void kernel_launch(void* const* d_in, const int* in_sizes, int n_in,
                              void* d_out, int out_size, void* d_ws, size_t ws_size,
                              hipStream_t stream)
{
    const int*   concept_seq = (const int*)  d_in[0];
    const int*   correct_seq = (const int*)  d_in[1];
    const int*   num_concept = (const int*)  d_in[2];
    const float* embed_key   = (const float*)d_in[3];
    const float* embed_value = (const float*)d_in[4];
    const float* Mk          = (const float*)d_in[5];
    const float* Mv0         = (const float*)d_in[6];
    const float* Wf          = (const float*)d_in[7];
    const float* bf          = (const float*)d_in[8];
    const float* We          = (const float*)d_in[9];
    const float* be          = (const float*)d_in[10];
    const float* Wa          = (const float*)d_in[11];
    const float* ba          = (const float*)d_in[12];
    const float* Wab         = (const float*)d_in[13];
    const float* bab         = (const float*)d_in[14];
    const float* Wd          = (const float*)d_in[15];
    const float* bd          = (const float*)d_in[16];
    float* out = (float*)d_out;

    float* wBuf = (float*)d_ws;                       // B*T*S
    float* eBuf = wBuf + (size_t)BB * TT * SS;        // B*T*D
    float* aBuf = eBuf + (size_t)BB * TT * DD;        // B*T*D
    float* rBuf = aBuf + (size_t)BB * TT * DD;        // B*T*D

    k1_precompute<<<BB * TT, 64, 0, stream>>>(
        concept_seq, correct_seq, num_concept,
        embed_key, embed_value, Mk, We, be, Wa, ba,
        wBuf, eBuf, aBuf);

    k2_scan<<<BB, 64, 0, stream>>>(wBuf, eBuf, aBuf, Mv0, rBuf);

    k3_output<<<BB * TT, 64, 0, stream>>>(
        concept_seq, embed_key, rBuf,
        Wf, bf, Wab, bab, Wd, bd, out);
}

// Round 3
// 320.943 us; speedup vs baseline: 1.5650x; 1.5650x over previous
//
#include <hip/hip_runtime.h>
#include <hip/hip_bf16.h>
#include <math.h>

#define BB 64
#define TT 500
#define DD 64
#define SS 50
#define NSG 4
#define CHUNK 20

__device__ __forceinline__ float sigmoidf_(float x) { return 1.0f / (1.0f + __expf(-x)); }

// ---------------------------------------------------------------------------
// Kernel 1: tables. blocks [0,ncon): wTab[c][50] = softmax(embed_key[c]·Mk^T)
//           blocks [ncon, ncon+nv): eTab[x] = sigmoid(ev@We+be), aTab = tanh(...)
// ---------------------------------------------------------------------------
__global__ __launch_bounds__(64) void k1_tables(
    const float* __restrict__ embed_key,
    const float* __restrict__ embed_value,
    const float* __restrict__ Mk,
    const float* __restrict__ We, const float* __restrict__ be,
    const float* __restrict__ Wa, const float* __restrict__ ba,
    int ncon, int nv,
    float* __restrict__ wTab, float* __restrict__ eTab, float* __restrict__ aTab)
{
    const int lane = threadIdx.x;
    if ((int)blockIdx.x < ncon) {
        const int c = blockIdx.x;
        __shared__ float mkS[SS][DD + 1];   // +1 pad: conflict-free row reads
        __shared__ float kS[DD];
        kS[lane] = embed_key[c * DD + lane];
        for (int s = 0; s < SS; ++s)
            mkS[s][lane] = Mk[s * DD + lane];
        __syncthreads();

        float sc = -1e30f;
        if (lane < SS) {
            float acc = 0.f;
            #pragma unroll
            for (int dd = 0; dd < DD; ++dd)
                acc = fmaf(kS[dd], mkS[lane][dd], acc);
            sc = acc;
        }
        float m = sc;
        #pragma unroll
        for (int off = 32; off >= 1; off >>= 1)
            m = fmaxf(m, __shfl_xor(m, off));
        float ex = (lane < SS) ? __expf(sc - m) : 0.f;
        float ssum = ex;
        #pragma unroll
        for (int off = 32; off >= 1; off >>= 1)
            ssum += __shfl_xor(ssum, off);
        if (lane < SS)
            wTab[c * SS + lane] = ex / ssum;
    } else {
        const int x = blockIdx.x - ncon;    // < nv
        __shared__ float vS[DD];
        vS[lane] = embed_value[x * DD + lane];
        __syncthreads();
        float acc_e = be[lane];
        float acc_a = ba[lane];
        #pragma unroll
        for (int i = 0; i < DD; ++i) {
            const float vi = vS[i];
            acc_e = fmaf(vi, We[i * DD + lane], acc_e);
            acc_a = fmaf(vi, Wa[i * DD + lane], acc_a);
        }
        eTab[x * DD + lane] = sigmoidf_(acc_e);
        aTab[x * DD + lane] = tanhf(acc_a);
    }
}

// ---------------------------------------------------------------------------
// Kernel 1b: expand w into zero-padded per-sg 16-float slices:
// wStr[bt][sg*16+j] = (s=start(sg)+j < end(sg)) ? wTab[c][s] : 0
// ---------------------------------------------------------------------------
__global__ __launch_bounds__(64) void k1b_expand(
    const int* __restrict__ cseq,
    const float* __restrict__ wTab,
    float* __restrict__ wStr)
{
    const int bt = blockIdx.x;
    const int lane = threadIdx.x;
    const int c = cseq[bt];
    const int sg = lane >> 4, j = lane & 15;
    const int st = (SS * sg) >> 2;
    const int en = (SS * (sg + 1)) >> 2;
    const int s = st + j;
    wStr[(size_t)bt * 64 + lane] = (s < en) ? wTab[c * SS + s] : 0.f;
}

// ---------------------------------------------------------------------------
// Kernel 2: scan. 64 blocks x 256 threads. Thread (sg = tid>>6, d = lane)
// owns Mv[start(sg)..end(sg)) in regs (<=13). Ping-pong register pipeline
// prefetches w (uniform float4 x4), e, a for t+1 while computing t.
// r partials -> LDS, reduced every CHUNK steps.
// ---------------------------------------------------------------------------
#define LOADSTAGE(W0, W1, W2, W3, EE, AA, tt)                                  \
    {                                                                          \
        const float4* wp_ = (const float4*)(wbase + (size_t)(tt) * 64);        \
        W0 = wp_[0]; W1 = wp_[1]; W2 = wp_[2]; W3 = wp_[3];                    \
        const int xx_ = xL[(tt)];                                              \
        EE = eTab[xx_ * DD + lane];                                            \
        AA = aTab[xx_ * DD + lane];                                            \
    }

#define UPD1(WW, JJ)                                                           \
    {                                                                          \
        const float mv_ = Mv[JJ];                                              \
        if ((JJ)&1) r1 = fmaf(WW, mv_, r1); else r0 = fmaf(WW, mv_, r0);       \
        Mv[JJ] = fmaf(-(WW), fmaf(e_, mv_, -a_), mv_);                         \
    }

#define STEP(W0, W1, W2, W3, EE, AA, TCUR)                                     \
    {                                                                          \
        const float e_ = EE, a_ = AA;                                          \
        float r0 = 0.f, r1 = 0.f;                                              \
        UPD1(W0.x, 0)  UPD1(W0.y, 1)  UPD1(W0.z, 2)  UPD1(W0.w, 3)             \
        UPD1(W1.x, 4)  UPD1(W1.y, 5)  UPD1(W1.z, 6)  UPD1(W1.w, 7)             \
        UPD1(W2.x, 8)  UPD1(W2.y, 9)  UPD1(W2.z, 10) UPD1(W2.w, 11)            \
        UPD1(W3.x, 12)                                                         \
        parts[TCUR][sg][lane] = r0 + r1;                                       \
    }

__global__ __launch_bounds__(256) void k2_scan(
    const int* __restrict__ cseq,
    const int* __restrict__ corr,
    const int* __restrict__ ncp,
    const float* __restrict__ wStr,
    const float* __restrict__ eTab,
    const float* __restrict__ aTab,
    const float* __restrict__ Mv0,
    float* __restrict__ rOut)
{
    const int b = blockIdx.x;
    const int tid = threadIdx.x;
    const int lane = tid & 63;
    const int sg = tid >> 6;
    const int nc = ncp[0];

    __shared__ int xL[TT];
    __shared__ float parts[CHUNK][NSG][DD];

    for (int i = tid; i < TT; i += 256) {
        const int c = cseq[b * TT + i];
        xL[i] = c + nc * corr[b * TT + i];
    }

    const int st = (SS * sg) >> 2;
    const int en = (SS * (sg + 1)) >> 2;
    float Mv[13];
    #pragma unroll
    for (int j = 0; j < 13; ++j) {
        const int s = st + j;
        Mv[j] = (s < en) ? Mv0[s * DD + lane] : 0.f;
    }
    __syncthreads();   // xL ready

    const float* wbase = wStr + (size_t)b * TT * 64 + sg * 16;

    float4 wA0, wA1, wA2, wA3, wB0, wB1, wB2, wB3;
    float eA, aA, eB, aB;

    LOADSTAGE(wA0, wA1, wA2, wA3, eA, aA, 0)

    for (int ch = 0; ch < TT / CHUNK; ++ch) {
        for (int tc = 0; tc < CHUNK; tc += 2) {
            const int t = ch * CHUNK + tc;
            // body A: compute t, prefetch t+1 into B  (t+1 <= 499 always)
            LOADSTAGE(wB0, wB1, wB2, wB3, eB, aB, t + 1)
            STEP(wA0, wA1, wA2, wA3, eA, aA, tc)
            // body B: compute t+1, prefetch t+2 into A
            if (t + 2 < TT) LOADSTAGE(wA0, wA1, wA2, wA3, eA, aA, t + 2)
            STEP(wB0, wB1, wB2, wB3, eB, aB, tc + 1)
        }
        __syncthreads();   // parts complete
        #pragma unroll
        for (int k = 0; k < (CHUNK * DD) / 256; ++k) {
            const int o = tid + k * 256;
            const int tc2 = o >> 6, d2 = o & 63;
            const float ssum = parts[tc2][0][d2] + parts[tc2][1][d2]
                             + parts[tc2][2][d2] + parts[tc2][3][d2];
            rOut[((size_t)b * TT + ch * CHUNK + tc2) * DD + d2] = ssum;
        }
        __syncthreads();   // reduce done before parts reused
    }
}

// ---------------------------------------------------------------------------
// Kernel 3: output head (unchanged from passing version)
// ---------------------------------------------------------------------------
__global__ __launch_bounds__(64) void k3_output(
    const int* __restrict__ concept_seq,
    const float* __restrict__ embed_key,
    const float* __restrict__ rIn,
    const float* __restrict__ Wf, const float* __restrict__ bf,
    const float* __restrict__ Wab, const float* __restrict__ bab,
    const float* __restrict__ Wd, const float* __restrict__ bd,
    float* __restrict__ out)
{
    const int bt = blockIdx.x;
    const int lane = threadIdx.x;
    __shared__ float rS[DD];
    __shared__ float kS[DD];
    const int c = concept_seq[bt];
    kS[lane] = embed_key[c * DD + lane];
    rS[lane] = rIn[(size_t)bt * DD + lane];
    __syncthreads();

    float acc = bf[lane];
    #pragma unroll
    for (int i = 0; i < DD; ++i)
        acc = fmaf(rS[i], Wf[i * DD + lane], acc);
    #pragma unroll
    for (int i = 0; i < DD; ++i)
        acc = fmaf(kS[i], Wf[(DD + i) * DD + lane], acc);
    const float f = tanhf(acc);

    float p = f * Wab[lane];
    float q = kS[lane] * Wd[lane];
    #pragma unroll
    for (int off = 32; off >= 1; off >>= 1) {
        p += __shfl_xor(p, off);
        q += __shfl_xor(q, off);
    }
    if (lane == 0) {
        const float stu  = tanhf(p + bab[0]);
        const float diff = tanhf(q + bd[0]);
        out[bt] = sigmoidf_(3.0f * stu - diff);
    }
}

// ---------------------------------------------------------------------------
extern "C" void kernel_launch(void* const* d_in, const int* in_sizes, int n_in,
                              void* d_out, int out_size, void* d_ws, size_t ws_size,
                              hipStream_t stream)
{
    const int*   concept_seq = (const int*)  d_in[0];
    const int*   correct_seq = (const int*)  d_in[1];
    const int*   num_concept = (const int*)  d_in[2];
    const float* embed_key   = (const float*)d_in[3];
    const float* embed_value = (const float*)d_in[4];
    const float* Mk          = (const float*)d_in[5];
    const float* Mv0         = (const float*)d_in[6];
    const float* Wf          = (const float*)d_in[7];
    const float* bf          = (const float*)d_in[8];
    const float* We          = (const float*)d_in[9];
    const float* be          = (const float*)d_in[10];
    const float* Wa          = (const float*)d_in[11];
    const float* ba          = (const float*)d_in[12];
    const float* Wab         = (const float*)d_in[13];
    const float* bab         = (const float*)d_in[14];
    const float* Wd          = (const float*)d_in[15];
    const float* bd          = (const float*)d_in[16];
    float* out = (float*)d_out;

    const int NCON = in_sizes[3] / DD;   // 1024
    const int NV   = in_sizes[4] / DD;   // 2048

    float* wTab = (float*)d_ws;                        // NCON*SS
    float* eTab = wTab + (size_t)NCON * SS;            // NV*DD
    float* aTab = eTab + (size_t)NV * DD;              // NV*DD
    float* wStr = aTab + (size_t)NV * DD;              // BB*TT*64 (16B-aligned)
    float* rBuf = wStr + (size_t)BB * TT * 64;         // BB*TT*DD

    k1_tables<<<NCON + NV, 64, 0, stream>>>(
        embed_key, embed_value, Mk, We, be, Wa, ba,
        NCON, NV, wTab, eTab, aTab);

    k1b_expand<<<BB * TT, 64, 0, stream>>>(concept_seq, wTab, wStr);

    k2_scan<<<BB, 256, 0, stream>>>(
        concept_seq, correct_seq, num_concept,
        wStr, eTab, aTab, Mv0, rBuf);

    k3_output<<<BB * TT, 64, 0, stream>>>(
        concept_seq, embed_key, rBuf,
        Wf, bf, Wab, bab, Wd, bd, out);
}

// Round 4
// 190.072 us; speedup vs baseline: 2.6426x; 1.6885x over previous
//
#include <hip/hip_runtime.h>
#include <hip/hip_bf16.h>
#include <math.h>

#define BB 64
#define TT 500
#define DD 64
#define SS 50
#define CH 20
#define NCH (TT / CH)   // 25

__device__ __forceinline__ float sigmoidf_(float x) { return 1.0f / (1.0f + __expf(-x)); }

// ---------------------------------------------------------------------------
// Kernel 1: tables. blocks [0,ncon): wTab[c][50] = softmax(embed_key[c]·Mk^T)
//           blocks [ncon, ncon+nv): eTab[x] = sigmoid(ev@We+be), aTab = tanh(...)
// ---------------------------------------------------------------------------
__global__ __launch_bounds__(64) void k1_tables(
    const float* __restrict__ embed_key,
    const float* __restrict__ embed_value,
    const float* __restrict__ Mk,
    const float* __restrict__ We, const float* __restrict__ be,
    const float* __restrict__ Wa, const float* __restrict__ ba,
    int ncon, int nv,
    float* __restrict__ wTab, float* __restrict__ eTab, float* __restrict__ aTab)
{
    const int lane = threadIdx.x;
    if ((int)blockIdx.x < ncon) {
        const int c = blockIdx.x;
        __shared__ float mkS[SS][DD + 1];
        __shared__ float kS[DD];
        kS[lane] = embed_key[c * DD + lane];
        for (int s = 0; s < SS; ++s)
            mkS[s][lane] = Mk[s * DD + lane];
        __syncthreads();

        float sc = -1e30f;
        if (lane < SS) {
            float acc = 0.f;
            #pragma unroll
            for (int dd = 0; dd < DD; ++dd)
                acc = fmaf(kS[dd], mkS[lane][dd], acc);
            sc = acc;
        }
        float m = sc;
        #pragma unroll
        for (int off = 32; off >= 1; off >>= 1)
            m = fmaxf(m, __shfl_xor(m, off));
        float ex = (lane < SS) ? __expf(sc - m) : 0.f;
        float ssum = ex;
        #pragma unroll
        for (int off = 32; off >= 1; off >>= 1)
            ssum += __shfl_xor(ssum, off);
        if (lane < SS)
            wTab[c * SS + lane] = ex / ssum;
    } else {
        const int x = blockIdx.x - ncon;
        __shared__ float vS[DD];
        vS[lane] = embed_value[x * DD + lane];
        __syncthreads();
        float acc_e = be[lane];
        float acc_a = ba[lane];
        #pragma unroll
        for (int i = 0; i < DD; ++i) {
            const float vi = vS[i];
            acc_e = fmaf(vi, We[i * DD + lane], acc_e);
            acc_a = fmaf(vi, Wa[i * DD + lane], acc_a);
        }
        eTab[x * DD + lane] = sigmoidf_(acc_e);
        aTab[x * DD + lane] = tanhf(acc_a);
    }
}

// ---------------------------------------------------------------------------
// Kernel 2: scan. grid = BB*4 blocks (b, sgB), 64 threads (lane = d).
// Block (b,sgB) owns s in [st,en) (12-13 states in regs). Chunked LDS
// staging, T14 issue-early/write-late: global loads for chunk ch+1 issued
// before computing chunk ch from LDS. r partials atomicAdd'ed into rOut.
// ---------------------------------------------------------------------------
#define STAGE_LOAD(T0)                                                       \
    {                                                                        \
        _Pragma("unroll")                                                    \
        for (int kk = 0; kk < 5; ++kk) {                                     \
            const int idx = lane + 64 * kk;                                  \
            const int tt = idx >> 4, j = idx & 15;                           \
            const int s = st + j;                                            \
            wr[kk] = (s < en) ? wTab[cL[(T0) + tt] * SS + s] : 0.f;          \
        }                                                                    \
        _Pragma("unroll")                                                    \
        for (int tt = 0; tt < CH; ++tt) {                                    \
            const int xx = xL[(T0) + tt];                                    \
            er[tt] = eTab[xx * DD + lane];                                   \
            ar[tt] = aTab[xx * DD + lane];                                   \
        }                                                                    \
    }

#define STAGE_WRITE()                                                        \
    {                                                                        \
        _Pragma("unroll")                                                    \
        for (int kk = 0; kk < 5; ++kk) wL[lane + 64 * kk] = wr[kk];          \
        _Pragma("unroll")                                                    \
        for (int tt = 0; tt < CH; ++tt) {                                    \
            eL[tt * DD + lane] = er[tt];                                     \
            aL[tt * DD + lane] = ar[tt];                                     \
        }                                                                    \
    }

#define UPD(WW, JJ)                                                          \
    {                                                                        \
        const float mv_ = Mv[JJ];                                            \
        if ((JJ) & 1) r1 = fmaf(WW, mv_, r1); else r0 = fmaf(WW, mv_, r0);   \
        Mv[JJ] = fmaf(-(WW), fmaf(e_, mv_, -a_), mv_);                       \
    }

__global__ __launch_bounds__(64) void k2_scan(
    const int* __restrict__ cseq,
    const int* __restrict__ corr,
    const int* __restrict__ ncp,
    const float* __restrict__ wTab,
    const float* __restrict__ eTab,
    const float* __restrict__ aTab,
    const float* __restrict__ Mv0,
    float* __restrict__ rOut)
{
    const int b = blockIdx.x >> 2;
    const int sgB = blockIdx.x & 3;
    const int lane = threadIdx.x;
    const int nc = ncp[0];

    __shared__ int xL[TT];
    __shared__ int cL[TT];
    __shared__ float __align__(16) wL[CH * 16];
    __shared__ float eL[CH * DD];
    __shared__ float aL[CH * DD];

    for (int i = lane; i < TT; i += 64) {
        const int c = cseq[b * TT + i];
        cL[i] = c;
        xL[i] = c + nc * corr[b * TT + i];
    }
    __syncthreads();

    const int st = (SS * sgB) >> 2;          // {0,12,25,37}
    const int en = (SS * (sgB + 1)) >> 2;    // {12,25,37,50}

    float Mv[13];
    #pragma unroll
    for (int j = 0; j < 13; ++j) {
        const int s = st + j;
        Mv[j] = (s < en) ? Mv0[s * DD + lane] : 0.f;
    }

    float wr[5], er[CH], ar[CH];

    STAGE_LOAD(0)
    STAGE_WRITE()
    __syncthreads();

    for (int ch = 0; ch < NCH; ++ch) {
        if (ch + 1 < NCH) STAGE_LOAD((ch + 1) * CH)   // in flight during compute

        #pragma unroll
        for (int tc = 0; tc < CH; ++tc) {
            const float4 w0 = *(const float4*)&wL[tc * 16 + 0];
            const float4 w1 = *(const float4*)&wL[tc * 16 + 4];
            const float4 w2 = *(const float4*)&wL[tc * 16 + 8];
            const float4 w3 = *(const float4*)&wL[tc * 16 + 12];
            const float e_ = eL[tc * DD + lane];
            const float a_ = aL[tc * DD + lane];
            float r0 = 0.f, r1 = 0.f;
            UPD(w0.x, 0)  UPD(w0.y, 1)  UPD(w0.z, 2)  UPD(w0.w, 3)
            UPD(w1.x, 4)  UPD(w1.y, 5)  UPD(w1.z, 6)  UPD(w1.w, 7)
            UPD(w2.x, 8)  UPD(w2.y, 9)  UPD(w2.z, 10) UPD(w2.w, 11)
            UPD(w3.x, 12)
            atomicAdd(&rOut[(size_t)(b * TT + ch * CH + tc) * DD + lane], r0 + r1);
        }
        __syncthreads();                  // LDS reads of this chunk done
        if (ch + 1 < NCH) STAGE_WRITE()   // waitcnt on globals lands here
        __syncthreads();
    }
}

// ---------------------------------------------------------------------------
// Kernel 3: output head as a tiled [64bt x 64j] fp32 GEMM with Wf in LDS.
// 500 blocks x 256 threads; thread (ty,tx) computes a 4bt x 4j register tile.
// ---------------------------------------------------------------------------
__global__ __launch_bounds__(256) void k3_output(
    const int* __restrict__ cseq,
    const float* __restrict__ embed_key,
    const float* __restrict__ rBuf,
    const float* __restrict__ Wf, const float* __restrict__ bf,
    const float* __restrict__ Wab, const float* __restrict__ bab,
    const float* __restrict__ Wd, const float* __restrict__ bd,
    float* __restrict__ out)
{
    const int tid = threadIdx.x;
    const int tx = tid & 15, ty = tid >> 4;
    const int bt0 = blockIdx.x * 64;

    __shared__ float __align__(16) wfS[128][64];    // Wf as-is
    __shared__ float __align__(16) catT[128][68];   // [i][bt], pad 68
    __shared__ float qS[64];
    __shared__ float redS[64][17];

    // stage Wf (8192 floats = 2048 float4)
    #pragma unroll
    for (int k = 0; k < 8; ++k) {
        const int idx = tid + k * 256;
        ((float4*)wfS)[idx] = ((const float4*)Wf)[idx];
    }

    // stage catT + que_diff partial. lane d = tid&63, group g = tid>>6
    {
        const int d = tid & 63;
        const int g = tid >> 6;
        const float wd = Wd[d];
        #pragma unroll
        for (int m = 0; m < 16; ++m) {
            const int btl = g + 4 * m;
            const int bt = bt0 + btl;
            const int c = cseq[bt];
            const float r  = rBuf[(size_t)bt * DD + d];
            const float kv = embed_key[c * DD + d];
            catT[d][btl] = r;
            catT[64 + d][btl] = kv;
            float q = kv * wd;
            #pragma unroll
            for (int off = 32; off >= 1; off >>= 1)
                q += __shfl_xor(q, off);
            if (d == 0) qS[btl] = q;
        }
    }
    __syncthreads();

    float acc[4][4] = {{0.f}};
    #pragma unroll 8
    for (int i = 0; i < 128; ++i) {
        const float4 wf = *(const float4*)&wfS[i][tx * 4];
        const float4 ct = *(const float4*)&catT[i][ty * 4];
        acc[0][0] = fmaf(ct.x, wf.x, acc[0][0]);
        acc[0][1] = fmaf(ct.x, wf.y, acc[0][1]);
        acc[0][2] = fmaf(ct.x, wf.z, acc[0][2]);
        acc[0][3] = fmaf(ct.x, wf.w, acc[0][3]);
        acc[1][0] = fmaf(ct.y, wf.x, acc[1][0]);
        acc[1][1] = fmaf(ct.y, wf.y, acc[1][1]);
        acc[1][2] = fmaf(ct.y, wf.z, acc[1][2]);
        acc[1][3] = fmaf(ct.y, wf.w, acc[1][3]);
        acc[2][0] = fmaf(ct.z, wf.x, acc[2][0]);
        acc[2][1] = fmaf(ct.z, wf.y, acc[2][1]);
        acc[2][2] = fmaf(ct.z, wf.z, acc[2][2]);
        acc[2][3] = fmaf(ct.z, wf.w, acc[2][3]);
        acc[3][0] = fmaf(ct.w, wf.x, acc[3][0]);
        acc[3][1] = fmaf(ct.w, wf.y, acc[3][1]);
        acc[3][2] = fmaf(ct.w, wf.z, acc[3][2]);
        acc[3][3] = fmaf(ct.w, wf.w, acc[3][3]);
    }

    // epilogue: f = tanh(acc + bf); stu-partial = sum_j f*Wab[j]
    #pragma unroll
    for (int ii = 0; ii < 4; ++ii) {
        float p = 0.f;
        #pragma unroll
        for (int jj = 0; jj < 4; ++jj) {
            const int j = tx * 4 + jj;
            const float f = tanhf(acc[ii][jj] + bf[j]);
            p = fmaf(f, Wab[j], p);
        }
        redS[ty * 4 + ii][tx] = p;
    }
    __syncthreads();

    if (tid < 64) {
        const int btl = tid;
        float s = 0.f;
        #pragma unroll
        for (int t2 = 0; t2 < 16; ++t2)
            s += redS[btl][t2];
        const float stu  = tanhf(s + bab[0]);
        const float diff = tanhf(qS[btl] + bd[0]);
        out[bt0 + btl] = sigmoidf_(3.0f * stu - diff);
    }
}

// ---------------------------------------------------------------------------
extern "C" void kernel_launch(void* const* d_in, const int* in_sizes, int n_in,
                              void* d_out, int out_size, void* d_ws, size_t ws_size,
                              hipStream_t stream)
{
    const int*   concept_seq = (const int*)  d_in[0];
    const int*   correct_seq = (const int*)  d_in[1];
    const int*   num_concept = (const int*)  d_in[2];
    const float* embed_key   = (const float*)d_in[3];
    const float* embed_value = (const float*)d_in[4];
    const float* Mk          = (const float*)d_in[5];
    const float* Mv0         = (const float*)d_in[6];
    const float* Wf          = (const float*)d_in[7];
    const float* bf          = (const float*)d_in[8];
    const float* We          = (const float*)d_in[9];
    const float* be          = (const float*)d_in[10];
    const float* Wa          = (const float*)d_in[11];
    const float* ba          = (const float*)d_in[12];
    const float* Wab         = (const float*)d_in[13];
    const float* bab         = (const float*)d_in[14];
    const float* Wd          = (const float*)d_in[15];
    const float* bd          = (const float*)d_in[16];
    float* out = (float*)d_out;

    const int NCON = in_sizes[3] / DD;   // 1024
    const int NV   = in_sizes[4] / DD;   // 2048

    float* wTab = (float*)d_ws;                        // NCON*SS
    float* eTab = wTab + (size_t)NCON * SS;            // NV*DD
    float* aTab = eTab + (size_t)NV * DD;              // NV*DD
    float* rBuf = aTab + (size_t)NV * DD;              // BB*TT*DD

    hipMemsetAsync(rBuf, 0, (size_t)BB * TT * DD * sizeof(float), stream);

    k1_tables<<<NCON + NV, 64, 0, stream>>>(
        embed_key, embed_value, Mk, We, be, Wa, ba,
        NCON, NV, wTab, eTab, aTab);

    k2_scan<<<BB * 4, 64, 0, stream>>>(
        concept_seq, correct_seq, num_concept,
        wTab, eTab, aTab, Mv0, rBuf);

    k3_output<<<(BB * TT) / 64, 256, 0, stream>>>(
        concept_seq, embed_key, rBuf,
        Wf, bf, Wab, bab, Wd, bd, out);
}